// Round 1
// baseline (996.417 us; speedup 1.0000x reference)
//
#include <hip/hip_runtime.h>
#include <stdint.h>

#define F_NODE 128
#define F_EDGE 32
#define HID    128
#define OUTF   64

// ---------------------------------------------------------------------------
// Preprocessing kernels
// ---------------------------------------------------------------------------

// Detect whether edge_index is int64 (reference dtype) or int32 (harness may
// downcast). Reads first 64 slots as int64; real int64 indices are all in
// [0,N); int32 data reinterpreted as int64 gives huge values (high word is
// the next random index, ==0 with prob 1e-5). Majority vote.
__global__ void detect_kernel(const void* ei, int N, int* flag) {
    const long long* p64 = (const long long*)ei;
    int t = threadIdx.x;
    long long v = p64[t];
    int ok = (v >= 0 && v < (long long)N) ? 1 : 0;
    unsigned long long m = __ballot(ok);
    if (t == 0) *flag = (__popcll(m) >= 32) ? 1 : 0;
}

__global__ void decode_kernel(const void* ei, int E, int N, const int* flag,
                              int* __restrict__ row, int* __restrict__ col) {
    int i = blockIdx.x * blockDim.x + threadIdx.x;
    if (i >= E) return;
    int r, c;
    if (*flag) {
        const long long* p = (const long long*)ei;
        r = (int)p[i];
        c = (int)p[E + i];
    } else {
        const int* p = (const int*)ei;
        r = p[i];
        c = p[E + i];
    }
    // safety clamp
    r = min(max(r, 0), N - 1);
    c = min(max(c, 0), N - 1);
    row[i] = r;
    col[i] = c;
}

__global__ void zero_kernel(int* p, int n) {
    int i = blockIdx.x * blockDim.x + threadIdx.x;
    if (i < n) p[i] = 0;
}

__global__ void hist_kernel(const int* __restrict__ col, int E, int* __restrict__ cnt) {
    int i = blockIdx.x * blockDim.x + threadIdx.x;
    if (i < E) atomicAdd(&cnt[col[i]], 1);
}

// 3-step exclusive scan over cnt[N] -> offs[N+1]
__global__ void scan1_kernel(const int* __restrict__ cnt, int N,
                             int* __restrict__ offs, int* __restrict__ bsum) {
    __shared__ int s[1024];
    int t = threadIdx.x;
    int i = blockIdx.x * 1024 + t;
    int v = (i < N) ? cnt[i] : 0;
    s[t] = v;
    __syncthreads();
    for (int d = 1; d < 1024; d <<= 1) {
        int x = (t >= d) ? s[t - d] : 0;
        __syncthreads();
        s[t] += x;
        __syncthreads();
    }
    if (i < N) offs[i + 1] = s[t];          // inclusive within block
    if (t == 1023) bsum[blockIdx.x] = s[1023];
}

__global__ void scan2_kernel(int* bsum, int nb) {
    __shared__ int s[1024];
    int t = threadIdx.x;
    int v = (t < nb) ? bsum[t] : 0;
    s[t] = v;
    __syncthreads();
    for (int d = 1; d < 1024; d <<= 1) {
        int x = (t >= d) ? s[t - d] : 0;
        __syncthreads();
        s[t] += x;
        __syncthreads();
    }
    if (t < nb) bsum[t] = s[t] - v;          // exclusive block offsets
}

__global__ void scan3_kernel(int* offs, int N, const int* __restrict__ bsum) {
    int i = blockIdx.x * blockDim.x + threadIdx.x;
    if (i == 0) offs[0] = 0;
    if (i < N) offs[i + 1] += bsum[i >> 10];
}

__global__ void init_kernel(const int* __restrict__ cnt, const int* __restrict__ offs,
                            int N, int* __restrict__ cursor, float* __restrict__ dinv) {
    int i = blockIdx.x * blockDim.x + threadIdx.x;
    if (i < N) {
        cursor[i] = offs[i];
        dinv[i] = rsqrtf((float)(cnt[i] + 1));   // +1 = self loop; deg >= 1 always
    }
}

// CSR fill: slot gets (src node, norm) packed as int2
__global__ void fill_kernel(const int* __restrict__ row, const int* __restrict__ col,
                            int E, int* __restrict__ cursor,
                            const float* __restrict__ dinv, int2* __restrict__ ent) {
    int i = blockIdx.x * blockDim.x + threadIdx.x;
    if (i >= E) return;
    int r = row[i], c = col[i];
    int pos = atomicAdd(&cursor[c], 1);
    float nm = dinv[r] * dinv[c];
    ent[pos] = make_int2(r, __float_as_int(nm));
}

// agg[n] = sum of edge_attr over edges with row==n (atomic scatter)
__global__ void agg_kernel(const float* __restrict__ ea, const int* __restrict__ row,
                           int E, float* __restrict__ agg) {
    int idx = blockIdx.x * blockDim.x + threadIdx.x;
    if (idx >= E * F_EDGE) return;
    int e = idx >> 5;
    int f = idx & 31;
    atomicAdd(&agg[(size_t)row[e] * F_EDGE + f], ea[idx]);
}

// ---------------------------------------------------------------------------
// GEMM: out[N,F] = concat(A[N,128], B[N,32]) @ W[160,F]
// 256 threads; per-thread tile NPT(=4) nodes x 8 feats; k-chunks of 32.
// ---------------------------------------------------------------------------
template <int F, int BN, int TX>
__global__ __launch_bounds__(256) void gemm_kernel(const float* __restrict__ A,
                                                   const float* __restrict__ B,
                                                   const float* __restrict__ W,
                                                   float* __restrict__ outp, int N) {
    constexpr int TY  = 256 / TX;
    constexpr int NPT = BN / TY;     // 4
    constexpr int KC  = 32;
    constexpr int IST = KC + 4;      // 36 (16B-aligned rows)
    constexpr int WST = F + 4;       // 132 / 68 (16B-aligned rows)
    __shared__ float in_lds[BN][IST];
    __shared__ float w_lds[KC][WST];

    int t  = threadIdx.x;
    int tx = t % TX;
    int ty = t / TX;
    int n0 = blockIdx.x * BN;
    int j0 = tx * 8;

    float acc[NPT][8];
#pragma unroll
    for (int i = 0; i < NPT; ++i)
#pragma unroll
        for (int f = 0; f < 8; ++f) acc[i][f] = 0.f;

    for (int c = 0; c < 5; ++c) {
        // stage input chunk (concat fused: chunks 0..3 from A, chunk 4 from B)
        const float* src = (c < 4) ? (A + c * KC) : B;
        int stride = (c < 4) ? F_NODE : F_EDGE;
        for (int l = t; l < BN * 8; l += 256) {
            int rr = l >> 3;
            int cc = (l & 7) * 4;
            int n = n0 + rr;
            if (n >= N) n = N - 1;
            float4 v = *(const float4*)(src + (size_t)n * stride + cc);
            *(float4*)&in_lds[rr][cc] = v;
        }
        // stage weight chunk
        for (int l = t; l < KC * F / 4; l += 256) {
            int rr = l / (F / 4);
            int cc = (l % (F / 4)) * 4;
            float4 v = *(const float4*)(W + (size_t)(c * KC + rr) * F + cc);
            *(float4*)&w_lds[rr][cc] = v;
        }
        __syncthreads();

#pragma unroll
        for (int kk = 0; kk < KC; kk += 4) {
            float4 a4[NPT];
#pragma unroll
            for (int i = 0; i < NPT; ++i)
                a4[i] = *(const float4*)&in_lds[ty * NPT + i][kk];
#pragma unroll
            for (int p = 0; p < 4; ++p) {
                float4 wa = *(const float4*)&w_lds[kk + p][j0];
                float4 wb = *(const float4*)&w_lds[kk + p][j0 + 4];
#pragma unroll
                for (int i = 0; i < NPT; ++i) {
                    float a = (p == 0) ? a4[i].x : (p == 1) ? a4[i].y
                              : (p == 2) ? a4[i].z : a4[i].w;
                    acc[i][0] = fmaf(a, wa.x, acc[i][0]);
                    acc[i][1] = fmaf(a, wa.y, acc[i][1]);
                    acc[i][2] = fmaf(a, wa.z, acc[i][2]);
                    acc[i][3] = fmaf(a, wa.w, acc[i][3]);
                    acc[i][4] = fmaf(a, wb.x, acc[i][4]);
                    acc[i][5] = fmaf(a, wb.y, acc[i][5]);
                    acc[i][6] = fmaf(a, wb.z, acc[i][6]);
                    acc[i][7] = fmaf(a, wb.w, acc[i][7]);
                }
            }
        }
        __syncthreads();
    }

#pragma unroll
    for (int i = 0; i < NPT; ++i) {
        int n = n0 + ty * NPT + i;
        if (n < N) {
            *(float4*)(outp + (size_t)n * F + j0) =
                make_float4(acc[i][0], acc[i][1], acc[i][2], acc[i][3]);
            *(float4*)(outp + (size_t)n * F + j0 + 4) =
                make_float4(acc[i][4], acc[i][5], acc[i][6], acc[i][7]);
        }
    }
}

// ---------------------------------------------------------------------------
// Conv aggregation: out[n] = sum_{e: dst==n} norm_e * h[src_e] + dinv[n]^2*h[n] + bias
// One wave per node; CSR gather (no atomics).
// ---------------------------------------------------------------------------
template <int F, bool RELU>
__global__ __launch_bounds__(256) void conv_kernel(const float* __restrict__ h,
                                                   const int* __restrict__ offs,
                                                   const int2* __restrict__ ent,
                                                   const float* __restrict__ dinv,
                                                   const float* __restrict__ bias,
                                                   float* __restrict__ outp, int N) {
    int wid  = threadIdx.x >> 6;
    int lane = threadIdx.x & 63;
    int n = blockIdx.x * 4 + wid;
    if (n >= N) return;
    float dn = dinv[n];
    float sw = dn * dn;
    int e0 = offs[n], e1 = offs[n + 1];

    if constexpr (F == 128) {
        float2 hv = *((const float2*)(h + (size_t)n * F) + lane);
        float a0 = sw * hv.x, a1 = sw * hv.y;
        for (int e = e0; e < e1; ++e) {
            int2 pr = ent[e];
            float w = __int_as_float(pr.y);
            float2 v = *((const float2*)(h + (size_t)pr.x * F) + lane);
            a0 = fmaf(w, v.x, a0);
            a1 = fmaf(w, v.y, a1);
        }
        float2 bv = *((const float2*)bias + lane);
        a0 += bv.x;
        a1 += bv.y;
        if (RELU) { a0 = fmaxf(a0, 0.f); a1 = fmaxf(a1, 0.f); }
        *((float2*)(outp + (size_t)n * F) + lane) = make_float2(a0, a1);
    } else {
        float a0 = sw * h[(size_t)n * F + lane];
        for (int e = e0; e < e1; ++e) {
            int2 pr = ent[e];
            float w = __int_as_float(pr.y);
            a0 = fmaf(w, h[(size_t)pr.x * F + lane], a0);
        }
        a0 += bias[lane];
        if (RELU) a0 = fmaxf(a0, 0.f);
        outp[(size_t)n * F + lane] = a0;
    }
}

// ---------------------------------------------------------------------------
extern "C" void kernel_launch(void* const* d_in, const int* in_sizes, int n_in,
                              void* d_out, int out_size, void* d_ws, size_t ws_size,
                              hipStream_t stream) {
    const float* x  = (const float*)d_in[0];
    const void*  ei = d_in[1];
    const float* ea = (const float*)d_in[2];
    const float* w1 = (const float*)d_in[3];
    const float* b1 = (const float*)d_in[4];
    const float* w2 = (const float*)d_in[5];
    const float* b2 = (const float*)d_in[6];
    float* out = (float*)d_out;

    int N = in_sizes[0] / F_NODE;
    int E = in_sizes[1] / 2;

    char* ws = (char*)d_ws;
    size_t off = 0;
    auto alloc = [&](size_t bytes) -> void* {
        void* p = ws + off;
        off = (off + bytes + 255) & ~(size_t)255;
        return p;
    };

    int*   flag   = (int*)alloc(256);
    int*   row    = (int*)alloc((size_t)E * 4);
    int*   col    = (int*)alloc((size_t)E * 4);
    int*   cnt    = (int*)alloc((size_t)N * 4);
    int*   offs   = (int*)alloc((size_t)(N + 1) * 4);
    int*   cursor = (int*)alloc((size_t)N * 4);
    float* dinv   = (float*)alloc((size_t)N * 4);
    int*   bsum   = (int*)alloc(4096);
    int2*  ent    = (int2*)alloc((size_t)E * 8);
    float* agg    = (float*)alloc((size_t)N * F_EDGE * 4);
    float* h1     = (float*)alloc((size_t)N * HID * 4);
    float* hr     = (float*)alloc((size_t)N * HID * 4);
    float* h2     = (float*)alloc((size_t)N * OUTF * 4);

    int gE = (E + 255) / 256;
    int gN = (N + 255) / 256;
    int nb = (N + 1023) / 1024;

    detect_kernel<<<1, 64, 0, stream>>>(ei, N, flag);
    decode_kernel<<<gE, 256, 0, stream>>>(ei, E, N, flag, row, col);
    zero_kernel<<<gN, 256, 0, stream>>>(cnt, N);
    zero_kernel<<<(N * F_EDGE + 255) / 256, 256, 0, stream>>>((int*)agg, N * F_EDGE);
    hist_kernel<<<gE, 256, 0, stream>>>(col, E, cnt);
    scan1_kernel<<<nb, 1024, 0, stream>>>(cnt, N, offs, bsum);
    scan2_kernel<<<1, 1024, 0, stream>>>(bsum, nb);
    scan3_kernel<<<gN, 256, 0, stream>>>(offs, N, bsum);
    init_kernel<<<gN, 256, 0, stream>>>(cnt, offs, N, cursor, dinv);
    fill_kernel<<<gE, 256, 0, stream>>>(row, col, E, cursor, dinv, ent);
    agg_kernel<<<(E * F_EDGE + 255) / 256, 256, 0, stream>>>(ea, row, E, agg);

    gemm_kernel<HID, 64, 16><<<(N + 63) / 64, 256, 0, stream>>>(x, agg, w1, h1, N);
    conv_kernel<HID, true><<<(N + 3) / 4, 256, 0, stream>>>(h1, offs, ent, dinv, b1, hr, N);
    gemm_kernel<OUTF, 128, 8><<<(N + 127) / 128, 256, 0, stream>>>(hr, agg, w2, h2, N);
    conv_kernel<OUTF, false><<<(N + 3) / 4, 256, 0, stream>>>(h2, offs, ent, dinv, b2, out, N);
}